// Round 1
// 1039.803 us; speedup vs baseline: 1.0924x; 1.0924x over previous
//
#include <hip/hip_runtime.h>
#include <hip/hip_bf16.h>

// FactoredLSTM on MI355X (gfx950).
// Phases:
//   A) convert/transpose weights fp32->bf16 [N][K]; gather embeddings; batched
//      GEMM chain U = X@Uw, S = U@S1w, Gx = S@Vw + (V_b + W_b)  (no h dependence)
//   B) ONE persistent kernel: 63 steps, grid-synced; W slice held in VGPRs,
//      c-state in LDS, h ring in global bf16.
//   C) batched output projection out = H@Pw + P_b  (134 GFLOP, bf16 MFMA,
//      m97-style global_load_lds staging)
//
// MFMA 16x16x32 bf16. A row-major [M][K], B pre-transposed [N][K].
// Layouts (verified): A/B frag idx=lane&15, k=(lane>>4)*8+j; C/D col=lane&15,
// row=(lane>>4)*4+reg.

typedef __bf16 bf16;
typedef bf16 bf16x8 __attribute__((ext_vector_type(8)));
typedef float f32x4 __attribute__((ext_vector_type(4)));

#define NB 32      // batch
#define NL 64      // seq len
#define NT 63      // timesteps (L-1)
#define NE 512     // emb
#define NS4 2048   // 4*STY
#define NS 512     // STY
#define NH 1024    // HID
#define NG 4096    // 4*HID
#define NV 32000   // vocab
#define MPAD 2048  // padded M (=NB*NT=2016 -> 2048)

#define RNB 32     // k_rnn grid: 32 blocks x 512 threads, each = 32 cols x 4 gates x M=32
#define FSTR 32    // flag stride in uints (128B) to avoid false sharing

__device__ __forceinline__ float sigmoidf_(float x) { return 1.0f / (1.0f + expf(-x)); }

// async global->LDS, 16B per lane; lds base must be wave-uniform (HW: base + lane*16)
__device__ __forceinline__ void gload_lds16(const bf16* g, bf16* l) {
  __builtin_amdgcn_global_load_lds(
      (const __attribute__((address_space(1))) unsigned int*)g,
      (__attribute__((address_space(3))) unsigned int*)l, 16, 0, 0);
}

// ---------------- transpose + convert: dst[C][R] = bf16(src[R][C]) -------------
__global__ void k_transpose_cvt(const float* __restrict__ src, bf16* __restrict__ dst,
                                int R, int C) {
  __shared__ float t[32][33];
  int bx = blockIdx.x * 32;  // C tile
  int by = blockIdx.y * 32;  // R tile
  int tx = threadIdx.x & 31, ty = threadIdx.x >> 5;  // ty in 0..7
#pragma unroll
  for (int i = 0; i < 32; i += 8)
    t[ty + i][tx] = src[(size_t)(by + ty + i) * C + (bx + tx)];
  __syncthreads();
#pragma unroll
  for (int i = 0; i < 32; i += 8)
    dst[(size_t)(bx + ty + i) * R + (by + tx)] = (bf16)t[tx][ty + i];
}

// ---------------- embedding gather into time-major X [MPAD][NE] bf16 -----------
__global__ void k_gather(const int* __restrict__ rnn, const float* __restrict__ embed,
                         bf16* __restrict__ X) {
  int r = blockIdx.x;
  if (r < NB * NT) {
    int t = r >> 5, b = r & 31;
    int tok = rnn[b * NL + t];
    const float* src = embed + (size_t)tok * NE;
    for (int e = threadIdx.x; e < NE; e += 256) X[(size_t)r * NE + e] = (bf16)src[e];
  } else {
    for (int e = threadIdx.x; e < NE; e += 256) X[(size_t)r * NE + e] = (bf16)0.0f;
  }
}

// ---------------- init h0 (bf16) from sentence_vector; zero step flags ---------
__global__ void k_init(const float* __restrict__ sv, bf16* __restrict__ h0,
                       unsigned* __restrict__ flags) {
  int i = blockIdx.x * 256 + threadIdx.x;
  if (i < RNB * FSTR) flags[i] = 0u;
  if (i < NB * NH) h0[i] = (bf16)sv[i];
}

// ---------------- combined bias V_b + W_b --------------------------------------
__global__ void k_bias2(const float* __restrict__ a, const float* __restrict__ b,
                        float* __restrict__ o) {
  int i = blockIdx.x * 256 + threadIdx.x;
  if (i < NG) o[i] = a[i] + b[i];
}

// ---------------- tiled MFMA GEMM: C = A[M][K] @ Bt[N][K]^T + bias -------------
// 128x128 tile, BK=32, 256 threads (4 waves, 2x2 of 64x64), m97-style
// global_load_lds(16) staging into unpadded stride-32 LDS.
// OUT_MODE 0: bf16 C [M][N]; 1: f32 C [M][N]; 2: f32 to d_out with row remap
template <int OUT_MODE>
__global__ __launch_bounds__(256, 2) void k_gemm(const bf16* __restrict__ A,
                                                 const bf16* __restrict__ Bt,
                                                 const float* __restrict__ bias,
                                                 void* __restrict__ Cp, int K, int N) {
  __shared__ bf16 As[128 * 32];
  __shared__ bf16 Bs[128 * 32];
  const int tid = threadIdx.x;
  const int m0 = blockIdx.y * 128, n0 = blockIdx.x * 128;
  const int lane = tid & 63, w = tid >> 6;
  const int l15 = lane & 15, kq = lane >> 4;
  const int m_off = (w & 1) * 64, n_off = (w >> 1) * 64;
  // staging: 8 chunks of 1KB per tile (wave-chunk = 64 lanes x 16B); wave w
  // does chunks 2w, 2w+1 of A and of B. chunk c, lane l -> row c*16+(l>>2),
  // k-offset (l&3)*8; LDS dest base As + c*512 elems (contiguous row-major).
  const int c0 = 2 * w, c1 = 2 * w + 1;
  const int sub = lane >> 2, kkl = (lane & 3) * 8;
  const bf16* pA0 = A + (size_t)(m0 + c0 * 16 + sub) * K + kkl;
  const bf16* pA1 = A + (size_t)(m0 + c1 * 16 + sub) * K + kkl;
  const bf16* pB0 = Bt + (size_t)(n0 + c0 * 16 + sub) * K + kkl;
  const bf16* pB1 = Bt + (size_t)(n0 + c1 * 16 + sub) * K + kkl;
  f32x4 acc[4][4] = {};
  for (int k0 = 0; k0 < K; k0 += 32) {
    __syncthreads();
    gload_lds16(pA0 + k0, &As[c0 * 512]);
    gload_lds16(pA1 + k0, &As[c1 * 512]);
    gload_lds16(pB0 + k0, &Bs[c0 * 512]);
    gload_lds16(pB1 + k0, &Bs[c1 * 512]);
    __syncthreads();
    bf16x8 a[4], b[4];
#pragma unroll
    for (int i = 0; i < 4; i++)
      a[i] = *(const bf16x8*)&As[(m_off + 16 * i + l15) * 32 + kq * 8];
#pragma unroll
    for (int j = 0; j < 4; j++)
      b[j] = *(const bf16x8*)&Bs[(n_off + 16 * j + l15) * 32 + kq * 8];
#pragma unroll
    for (int i = 0; i < 4; i++)
#pragma unroll
      for (int j = 0; j < 4; j++)
        acc[i][j] = __builtin_amdgcn_mfma_f32_16x16x32_bf16(a[i], b[j], acc[i][j], 0, 0, 0);
  }
#pragma unroll
  for (int j = 0; j < 4; j++) {
    const int col = n0 + n_off + 16 * j + l15;
    const float bv = bias[col];
#pragma unroll
    for (int i = 0; i < 4; i++) {
#pragma unroll
      for (int r = 0; r < 4; r++) {
        const int row = m0 + m_off + 16 * i + kq * 4 + r;
        const float v = acc[i][j][r] + bv;
        if (OUT_MODE == 0) {
          ((bf16*)Cp)[(size_t)row * N + col] = (bf16)v;
        } else if (OUT_MODE == 1) {
          ((float*)Cp)[(size_t)row * N + col] = v;
        } else {
          if (row < NB * NT) {
            int t = row >> 5, b = row & 31;
            ((float*)Cp)[((size_t)b * NT + t) * NV + col] = v;
          }
        }
      }
    }
  }
}

// ---------------- persistent recurrence ----------------------------------------
// 32 blocks x 512 threads (8 waves). Block b owns gate-cols [32b, 32b+32) for
// ALL 4 gates and the FULL batch M=32 (no W replication: W partitions exactly,
// 128 VGPR/lane). Wave w: gate = w&3, col-half = w>>2 (16 cols), two 16-row
// MFMA tiles sharing breg.
// Step sync: flag-array sequence barrier instead of one RMW'd counter —
//   producer: plain h stores -> __syncthreads (vmcnt drain) -> wave0:
//   release fence (L2 writeback) -> relaxed store flags[bid] = t+1;
//   consumer: wave0 polls all 32 flags with RELAXED agent loads (no per-poll
//   cache maintenance), then ONE acquire fence (invalidate), __syncthreads.
// Gx[t] is prefetched into registers at loop top, concurrent with h staging,
// so the epilogue has no cold global loads on the critical path.
__global__ __launch_bounds__(512) void k_rnn(const bf16* __restrict__ Wt,
                                             const float* __restrict__ Gx,
                                             const float* __restrict__ sv,
                                             bf16* __restrict__ hb,
                                             unsigned* __restrict__ flags) {
  __shared__ bf16 hs[32 * 1032];   // h full batch, row stride 1032 (bank rotate)
  __shared__ float gl[4][32][32];  // gate partials [gate][batch][local col]
  __shared__ float cs[32][32];     // c state      [batch][local col]
  const int tid = threadIdx.x;
  const int lane = tid & 63, wid = tid >> 6;
  const int g = wid & 3, ch = wid >> 2;  // gate 0..3, col-half 0..1
  const int l15 = lane & 15, kq = lane >> 4;
  const int j0 = blockIdx.x * 32;        // global col base of this block
  const int bb_e = tid >> 4, jj_e = tid & 15;  // epilogue cell (+ jj_e+16)

  // c init (each thread owns its 2 cells for all 63 steps; no sync needed)
  cs[bb_e][jj_e] = sv[bb_e * NH + j0 + jj_e];
  cs[bb_e][jj_e + 16] = sv[bb_e * NH + j0 + jj_e + 16];

  // W slice -> registers: wave (g,ch) col j0+ch*16+l15; lane holds
  // wrow[k*32 + kq*8 .. +7] for k=0..31  (128 VGPRs)
  const bf16* wrow = Wt + (size_t)(g * NH + j0 + ch * 16 + l15) * NH;
  bf16x8 breg[32];
#pragma unroll
  for (int k = 0; k < 32; k++) breg[k] = *(const bf16x8*)&wrow[k * 32 + kq * 8];

  for (int t = 0; t < NT; t++) {
    // prefetch Gx[t] epilogue operands (independent of h; hides under staging)
    const float* gx0 = Gx + (size_t)t * NB * NG + (size_t)bb_e * NG + j0;
    float gxr[8];
#pragma unroll
    for (int u = 0; u < 2; u++)
#pragma unroll
      for (int gg = 0; gg < 4; gg++)
        gxr[u * 4 + gg] = gx0[gg * NH + jj_e + u * 16];
    // stage h[t] (32 x 1024 bf16 = 64KB): 512 threads x 8 x 16B, coalesced
    const bf16* hp = hb + (size_t)t * NB * NH;
#pragma unroll
    for (int q = 0; q < 8; q++) {
      int idx = tid + 512 * q;        // 4096 chunks of 8 elems
      int row = idx >> 7, col = (idx & 127) * 8;
      *(bf16x8*)&hs[row * 1032 + col] = *(const bf16x8*)&hp[row * NH + col];
    }
    __syncthreads();
    f32x4 acc0 = {}, acc1 = {};  // rows 0-15 / 16-31
#pragma unroll
    for (int k = 0; k < 32; k++) {
      bf16x8 a0 = *(const bf16x8*)&hs[l15 * 1032 + k * 32 + kq * 8];
      bf16x8 a1 = *(const bf16x8*)&hs[(16 + l15) * 1032 + k * 32 + kq * 8];
      acc0 = __builtin_amdgcn_mfma_f32_16x16x32_bf16(a0, breg[k], acc0, 0, 0, 0);
      acc1 = __builtin_amdgcn_mfma_f32_16x16x32_bf16(a1, breg[k], acc1, 0, 0, 0);
    }
#pragma unroll
    for (int r = 0; r < 4; r++) {
      gl[g][kq * 4 + r][ch * 16 + l15] = acc0[r];
      gl[g][16 + kq * 4 + r][ch * 16 + l15] = acc1[r];
    }
    __syncthreads();
    // epilogue: thread -> (batch bb_e, cols jj_e, jj_e+16); pure VALU + LDS
    bf16* hw = hb + (size_t)(t + 1) * NB * NH + (size_t)bb_e * NH + j0;
#pragma unroll
    for (int u = 0; u < 2; u++) {
      const int jj = jj_e + u * 16;
      float gi = gl[0][bb_e][jj] + gxr[u * 4 + 0];
      float gf = gl[1][bb_e][jj] + gxr[u * 4 + 1];
      float go = gl[2][bb_e][jj] + gxr[u * 4 + 2];
      float gc = gl[3][bb_e][jj] + gxr[u * 4 + 3];
      float cp = cs[bb_e][jj];
      float cn = sigmoidf_(gf) * cp + sigmoidf_(gi) * tanhf(gc);
      float hn = sigmoidf_(go) * cn;
      cs[bb_e][jj] = cn;
      hw[jj] = (bf16)hn;
    }
    // flag-array step barrier (skip after last step; stream order covers Phase C)
    if (t + 1 < NT) {
      __syncthreads();  // all waves' h stores drained to L2 (vmcnt 0 + barrier)
      if (wid == 0) {
        __builtin_amdgcn_fence(__ATOMIC_RELEASE, "agent");  // writeback dirty h
        if (lane == 0)
          __hip_atomic_store(&flags[blockIdx.x * FSTR], (unsigned)(t + 1),
                             __ATOMIC_RELAXED, __HIP_MEMORY_SCOPE_AGENT);
        const unsigned tgt = (unsigned)(t + 1);
        for (;;) {
          unsigned v = __hip_atomic_load(&flags[(lane & 31) * FSTR],
                                         __ATOMIC_RELAXED, __HIP_MEMORY_SCOPE_AGENT);
          if (__all((int)(v >= tgt))) break;
          __builtin_amdgcn_s_sleep(1);
        }
        __builtin_amdgcn_fence(__ATOMIC_ACQUIRE, "agent");  // invalidate stale h
      }
      __syncthreads();
    }
  }
}

extern "C" void kernel_launch(void* const* d_in, const int* in_sizes, int n_in,
                              void* d_out, int out_size, void* d_ws, size_t ws_size,
                              hipStream_t stream) {
  const int* rnn = (const int*)d_in[0];
  const float* sv = (const float*)d_in[1];
  const float* embed = (const float*)d_in[2];
  const float* U_w = (const float*)d_in[3];
  const float* U_b = (const float*)d_in[4];
  const float* S1_w = (const float*)d_in[5];
  const float* S1_b = (const float*)d_in[6];
  const float* V_w = (const float*)d_in[7];
  const float* V_b = (const float*)d_in[8];
  const float* W_w = (const float*)d_in[9];
  const float* W_b = (const float*)d_in[10];
  const float* P_w = (const float*)d_in[11];
  const float* P_b = (const float*)d_in[12];
  float* out = (float*)d_out;

  char* ws = (char*)d_ws;
  size_t off = 0;
  auto alloc = [&](size_t bytes) -> void* {
    void* p = ws + off;
    off += (bytes + 255) & ~(size_t)255;
    return p;
  };
  bf16* Pt = (bf16*)alloc((size_t)NV * NH * 2);           // P_w^T
  float* Gx = (float*)alloc((size_t)MPAD * NG * 4);       // gate preactivations
  bf16* Ub = (bf16*)alloc((size_t)MPAD * NS4 * 2);        // U (bf16)
  bf16* Wt = (bf16*)alloc((size_t)NG * NH * 2);           // W_w^T
  bf16* hb = (bf16*)alloc((size_t)(MPAD + 32) * NH * 2);  // h ring (row0=h0)
  bf16* Vt = (bf16*)alloc((size_t)NG * NS * 2);           // V_w^T
  bf16* Xb = (bf16*)alloc((size_t)MPAD * NE * 2);         // gathered emb
  bf16* Ut = (bf16*)alloc((size_t)NS4 * NE * 2);          // U_w^T
  bf16* S1t = (bf16*)alloc((size_t)NS * NS4 * 2);         // S1_w^T
  bf16* Sb = (bf16*)alloc((size_t)MPAD * NS * 2);         // S (bf16)
  float* vbwb = (float*)alloc((size_t)NG * 4);            // V_b + W_b
  unsigned* flags = (unsigned*)alloc((size_t)RNB * FSTR * 4);  // step flags
  (void)in_sizes; (void)n_in; (void)out_size; (void)ws_size;

  // Phase A0: weight conversion (transpose to [N][K] bf16)
  k_transpose_cvt<<<dim3(NS4 / 32, NE / 32), 256, 0, stream>>>(U_w, Ut, NE, NS4);
  k_transpose_cvt<<<dim3(NS / 32, NS4 / 32), 256, 0, stream>>>(S1_w, S1t, NS4, NS);
  k_transpose_cvt<<<dim3(NG / 32, NS / 32), 256, 0, stream>>>(V_w, Vt, NS, NG);
  k_transpose_cvt<<<dim3(NG / 32, NH / 32), 256, 0, stream>>>(W_w, Wt, NH, NG);
  k_transpose_cvt<<<dim3(NV / 32, NH / 32), 256, 0, stream>>>(P_w, Pt, NH, NV);
  k_bias2<<<NG / 256, 256, 0, stream>>>(V_b, W_b, vbwb);
  k_init<<<(NB * NH + 255) / 256, 256, 0, stream>>>(sv, hb, flags);
  k_gather<<<MPAD, 256, 0, stream>>>(rnn, embed, Xb);

  // Phase A1: batched pre-GEMMs over all (t,b)
  k_gemm<0><<<dim3(NS4 / 128, MPAD / 128), 256, 0, stream>>>(Xb, Ut, U_b, Ub, NE, NS4);
  k_gemm<0><<<dim3(NS / 128, MPAD / 128), 256, 0, stream>>>(Ub, S1t, S1_b, Sb, NS4, NS);
  k_gemm<1><<<dim3(NG / 128, MPAD / 128), 256, 0, stream>>>(Sb, Vt, vbwb, Gx, NS, NG);

  // Phase B: persistent recurrence (single dispatch, internal flag barrier)
  k_rnn<<<RNB, 512, 0, stream>>>(Wt, Gx, sv, hb, flags);

  // Phase C: output projection for all (t,b), remapped to out[b][t][v]
  k_gemm<2><<<dim3(NV / 128, MPAD / 128), 256, 0, stream>>>(hb + (size_t)NB * NH, Pt,
                                                            P_b, out, NH, NV);
}

// Round 2
// 1006.750 us; speedup vs baseline: 1.1283x; 1.0328x over previous
//
#include <hip/hip_runtime.h>
#include <hip/hip_bf16.h>

// FactoredLSTM on MI355X (gfx950).
// Phases:
//   A) convert/transpose weights fp32->bf16 [N][K]; gather embeddings; batched
//      GEMM chain U = X@Uw, S = U@S1w, Gx = S@Vw + (V_b + W_b)  (no h dependence)
//   B) ONE persistent kernel: 63 steps, grid-synced; W slice in VGPRs/AGPRs,
//      c-state in LDS, h ring in global bf16.
//      Sync design (fence-free): h stores are write-through sc0/sc1 (acked at
//      the memory-side coherence point => vmcnt(0) IS the release), flags are
//      relaxed agent atomics (bypass L2), h loads are plain (ring buffer =>
//      no stale L2 lines can exist). No buffer_wbl2 / buffer_inv per step.
//   C) batched output projection out = H@Pw + P_b  (134 GFLOP, bf16 MFMA,
//      m97-style global_load_lds staging)
//
// MFMA 16x16x32 bf16. A row-major [M][K], B pre-transposed [N][K].
// Layouts (verified): A/B frag idx=lane&15, k=(lane>>4)*8+j; C/D col=lane&15,
// row=(lane>>4)*4+reg.

typedef __bf16 bf16;
typedef bf16 bf16x8 __attribute__((ext_vector_type(8)));
typedef float f32x4 __attribute__((ext_vector_type(4)));
typedef float f32x2 __attribute__((ext_vector_type(2)));

#define NB 32      // batch
#define NL 64      // seq len
#define NT 63      // timesteps (L-1)
#define NE 512     // emb
#define NS4 2048   // 4*STY
#define NS 512     // STY
#define NH 1024    // HID
#define NG 4096    // 4*HID
#define NV 32000   // vocab
#define MPAD 2048  // padded M (=NB*NT=2016 -> 2048)

#define RNB 32     // k_rnn grid: 32 blocks x 512 threads, each = 32 cols x 4 gates x M=32
#define FSTR 32    // flag stride in uints (128B) to avoid false sharing

__device__ __forceinline__ float sigmoidf_(float x) { return 1.0f / (1.0f + expf(-x)); }

// async global->LDS, 16B per lane; lds base must be wave-uniform (HW: base + lane*16)
__device__ __forceinline__ void gload_lds16(const bf16* g, bf16* l) {
  __builtin_amdgcn_global_load_lds(
      (const __attribute__((address_space(1))) unsigned int*)g,
      (__attribute__((address_space(3))) unsigned int*)l, 16, 0, 0);
}

// write-through store, bypasses L1+L2 (coherence point = Infinity Cache).
// vmcnt(0) after this == cross-XCD release for the stored data.
__device__ __forceinline__ void store_dword_wt(void* p, unsigned v) {
  asm volatile("global_store_dword %0, %1, off sc0 sc1" ::"v"(p), "v"(v) : "memory");
}

// ---------------- transpose + convert: dst[C][R] = bf16(src[R][C]) -------------
__global__ void k_transpose_cvt(const float* __restrict__ src, bf16* __restrict__ dst,
                                int R, int C) {
  __shared__ float t[32][33];
  int bx = blockIdx.x * 32;  // C tile
  int by = blockIdx.y * 32;  // R tile
  int tx = threadIdx.x & 31, ty = threadIdx.x >> 5;  // ty in 0..7
#pragma unroll
  for (int i = 0; i < 32; i += 8)
    t[ty + i][tx] = src[(size_t)(by + ty + i) * C + (bx + tx)];
  __syncthreads();
#pragma unroll
  for (int i = 0; i < 32; i += 8)
    dst[(size_t)(bx + ty + i) * R + (by + tx)] = (bf16)t[tx][ty + i];
}

// ---------------- embedding gather into time-major X [MPAD][NE] bf16 -----------
__global__ void k_gather(const int* __restrict__ rnn, const float* __restrict__ embed,
                         bf16* __restrict__ X) {
  int r = blockIdx.x;
  if (r < NB * NT) {
    int t = r >> 5, b = r & 31;
    int tok = rnn[b * NL + t];
    const float* src = embed + (size_t)tok * NE;
    for (int e = threadIdx.x; e < NE; e += 256) X[(size_t)r * NE + e] = (bf16)src[e];
  } else {
    for (int e = threadIdx.x; e < NE; e += 256) X[(size_t)r * NE + e] = (bf16)0.0f;
  }
}

// ---------------- init h0 (bf16) from sentence_vector; zero step flags ---------
__global__ void k_init(const float* __restrict__ sv, bf16* __restrict__ h0,
                       unsigned* __restrict__ flags) {
  int i = blockIdx.x * 256 + threadIdx.x;
  if (i < RNB * FSTR) flags[i] = 0u;
  if (i < NB * NH) h0[i] = (bf16)sv[i];
}

// ---------------- combined bias V_b + W_b --------------------------------------
__global__ void k_bias2(const float* __restrict__ a, const float* __restrict__ b,
                        float* __restrict__ o) {
  int i = blockIdx.x * 256 + threadIdx.x;
  if (i < NG) o[i] = a[i] + b[i];
}

// ---------------- tiled MFMA GEMM: C = A[M][K] @ Bt[N][K]^T + bias -------------
// 128x128 tile, BK=32, 256 threads (4 waves, 2x2 of 64x64), m97-style
// global_load_lds(16) staging into unpadded stride-32 LDS.
// OUT_MODE 0: bf16 C [M][N]; 1: f32 C [M][N]; 2: f32 to d_out with row remap
template <int OUT_MODE>
__global__ __launch_bounds__(256, 2) void k_gemm(const bf16* __restrict__ A,
                                                 const bf16* __restrict__ Bt,
                                                 const float* __restrict__ bias,
                                                 void* __restrict__ Cp, int K, int N) {
  __shared__ bf16 As[128 * 32];
  __shared__ bf16 Bs[128 * 32];
  const int tid = threadIdx.x;
  const int m0 = blockIdx.y * 128, n0 = blockIdx.x * 128;
  const int lane = tid & 63, w = tid >> 6;
  const int l15 = lane & 15, kq = lane >> 4;
  const int m_off = (w & 1) * 64, n_off = (w >> 1) * 64;
  // staging: 8 chunks of 1KB per tile (wave-chunk = 64 lanes x 16B); wave w
  // does chunks 2w, 2w+1 of A and of B. chunk c, lane l -> row c*16+(l>>2),
  // k-offset (l&3)*8; LDS dest base As + c*512 elems (contiguous row-major).
  const int c0 = 2 * w, c1 = 2 * w + 1;
  const int sub = lane >> 2, kkl = (lane & 3) * 8;
  const bf16* pA0 = A + (size_t)(m0 + c0 * 16 + sub) * K + kkl;
  const bf16* pA1 = A + (size_t)(m0 + c1 * 16 + sub) * K + kkl;
  const bf16* pB0 = Bt + (size_t)(n0 + c0 * 16 + sub) * K + kkl;
  const bf16* pB1 = Bt + (size_t)(n0 + c1 * 16 + sub) * K + kkl;
  f32x4 acc[4][4] = {};
  for (int k0 = 0; k0 < K; k0 += 32) {
    __syncthreads();
    gload_lds16(pA0 + k0, &As[c0 * 512]);
    gload_lds16(pA1 + k0, &As[c1 * 512]);
    gload_lds16(pB0 + k0, &Bs[c0 * 512]);
    gload_lds16(pB1 + k0, &Bs[c1 * 512]);
    __syncthreads();
    bf16x8 a[4], b[4];
#pragma unroll
    for (int i = 0; i < 4; i++)
      a[i] = *(const bf16x8*)&As[(m_off + 16 * i + l15) * 32 + kq * 8];
#pragma unroll
    for (int j = 0; j < 4; j++)
      b[j] = *(const bf16x8*)&Bs[(n_off + 16 * j + l15) * 32 + kq * 8];
#pragma unroll
    for (int i = 0; i < 4; i++)
#pragma unroll
      for (int j = 0; j < 4; j++)
        acc[i][j] = __builtin_amdgcn_mfma_f32_16x16x32_bf16(a[i], b[j], acc[i][j], 0, 0, 0);
  }
#pragma unroll
  for (int j = 0; j < 4; j++) {
    const int col = n0 + n_off + 16 * j + l15;
    const float bv = bias[col];
#pragma unroll
    for (int i = 0; i < 4; i++) {
#pragma unroll
      for (int r = 0; r < 4; r++) {
        const int row = m0 + m_off + 16 * i + kq * 4 + r;
        const float v = acc[i][j][r] + bv;
        if (OUT_MODE == 0) {
          ((bf16*)Cp)[(size_t)row * N + col] = (bf16)v;
        } else if (OUT_MODE == 1) {
          ((float*)Cp)[(size_t)row * N + col] = v;
        } else {
          if (row < NB * NT) {
            int t = row >> 5, b = row & 31;
            ((float*)Cp)[((size_t)b * NT + t) * NV + col] = v;
          }
        }
      }
    }
  }
}

// ---------------- persistent recurrence ----------------------------------------
// 32 blocks x 512 threads (8 waves). Block b owns gate-cols [32b, 32b+32) for
// ALL 4 gates and the FULL batch M=32 (W partitions exactly, 128 regs/lane).
// Wave w: gate = w&3, col-half = w>>2 (16 cols), two 16-row MFMA tiles sharing breg.
// Fence-free step barrier:
//   producer: sc0/sc1 write-through h stores -> s_waitcnt vmcnt(0) (== release,
//   acked at IF$) -> raw s_barrier -> wave0 relaxed-atomic flag store;
//   consumer: wave0 polls 32 flags (relaxed agent loads, bypass L2), raw
//   s_barrier + compiler memory fence; h restage uses PLAIN loads — safe
//   because the h ring never reuses addresses (no stale L2 copy can exist;
//   first touch is post-poll and fills from IF$, shared by co-XCD blocks).
__global__ __launch_bounds__(512) void k_rnn(const bf16* __restrict__ Wt,
                                             const float* __restrict__ Gx,
                                             const float* __restrict__ sv,
                                             bf16* __restrict__ hb,
                                             unsigned* __restrict__ flags) {
  __shared__ bf16 hs[32 * 1032];   // h full batch, row stride 1032 (bank rotate)
  __shared__ float gl[4][32][33];  // gate partials [gate][batch][local col] (+pad)
  __shared__ float cs[32][33];     // c state      [batch][local col] (+pad)
  const int tid = threadIdx.x;
  const int lane = tid & 63, wid = tid >> 6;
  const int g = wid & 3, ch = wid >> 2;  // gate 0..3, col-half 0..1
  const int l15 = lane & 15, kq = lane >> 4;
  const int j0 = blockIdx.x * 32;        // global col base of this block
  const int bb_e = tid >> 4;             // epilogue batch row 0..31
  const int jp = tid & 15;               // epilogue col-pair: local cols 2jp, 2jp+1
  const int c0e = 2 * jp, c1e = 2 * jp + 1;

  // c init (each thread owns its 2 cells for all 63 steps; no sync needed)
  cs[bb_e][c0e] = sv[bb_e * NH + j0 + c0e];
  cs[bb_e][c1e] = sv[bb_e * NH + j0 + c1e];

  // W slice -> registers: wave (g,ch) col j0+ch*16+l15; lane holds
  // wrow[k*32 + kq*8 .. +7] for k=0..31  (128 regs)
  const bf16* wrow = Wt + (size_t)(g * NH + j0 + ch * 16 + l15) * NH;
  bf16x8 breg[32];
#pragma unroll
  for (int k = 0; k < 32; k++) breg[k] = *(const bf16x8*)&wrow[k * 32 + kq * 8];

  for (int t = 0; t < NT; t++) {
    // prefetch Gx[t] epilogue operands (independent of h; hides under staging)
    const float* gx0 = Gx + (size_t)t * NB * NG + (size_t)bb_e * NG + j0 + c0e;
    f32x2 gxr[4];
#pragma unroll
    for (int gg = 0; gg < 4; gg++) gxr[gg] = *(const f32x2*)&gx0[gg * NH];
    // stage h[t] (32 x 1024 bf16 = 64KB): 512 threads x 8 x 16B, coalesced
    const bf16* hp = hb + (size_t)t * NB * NH;
#pragma unroll
    for (int q = 0; q < 8; q++) {
      int idx = tid + 512 * q;        // 4096 chunks of 8 elems
      int row = idx >> 7, col = (idx & 127) * 8;
      *(bf16x8*)&hs[row * 1032 + col] = *(const bf16x8*)&hp[row * NH + col];
    }
    __syncthreads();
    f32x4 acc0 = {}, acc1 = {};  // rows 0-15 / 16-31
#pragma unroll
    for (int k = 0; k < 32; k++) {
      bf16x8 a0 = *(const bf16x8*)&hs[l15 * 1032 + k * 32 + kq * 8];
      bf16x8 a1 = *(const bf16x8*)&hs[(16 + l15) * 1032 + k * 32 + kq * 8];
      acc0 = __builtin_amdgcn_mfma_f32_16x16x32_bf16(a0, breg[k], acc0, 0, 0, 0);
      acc1 = __builtin_amdgcn_mfma_f32_16x16x32_bf16(a1, breg[k], acc1, 0, 0, 0);
    }
#pragma unroll
    for (int r = 0; r < 4; r++) {
      gl[g][kq * 4 + r][ch * 16 + l15] = acc0[r];
      gl[g][16 + kq * 4 + r][ch * 16 + l15] = acc1[r];
    }
    __syncthreads();
    // epilogue: thread -> (batch bb_e, local cols 2jp, 2jp+1); pure VALU + LDS,
    // single packed 4B write-through h store.
    {
      float hn2[2];
#pragma unroll
      for (int u = 0; u < 2; u++) {
        const int jj = c0e + u;
        float gi = gl[0][bb_e][jj] + gxr[0][u];
        float gf = gl[1][bb_e][jj] + gxr[1][u];
        float go = gl[2][bb_e][jj] + gxr[2][u];
        float gc = gl[3][bb_e][jj] + gxr[3][u];
        float cp = cs[bb_e][jj];
        float cn = sigmoidf_(gf) * cp + sigmoidf_(gi) * tanhf(gc);
        hn2[u] = sigmoidf_(go) * cn;
        cs[bb_e][jj] = cn;
      }
      unsigned short b0 = __builtin_bit_cast(unsigned short, (bf16)hn2[0]);
      unsigned short b1 = __builtin_bit_cast(unsigned short, (bf16)hn2[1]);
      unsigned pv = (unsigned)b0 | ((unsigned)b1 << 16);
      bf16* hw = hb + (size_t)(t + 1) * NB * NH + (size_t)bb_e * NH + j0 + c0e;
      store_dword_wt(hw, pv);
    }
    // fence-free step barrier (skip after last step; kernel-end release covers C)
    if (t + 1 < NT) {
      asm volatile("s_waitcnt vmcnt(0)" ::: "memory");  // h acked at IF$ (release)
      __builtin_amdgcn_s_barrier();                     // all waves released
      if (wid == 0) {
        if (lane == 0)
          __hip_atomic_store(&flags[blockIdx.x * FSTR], (unsigned)(t + 1),
                             __ATOMIC_RELAXED, __HIP_MEMORY_SCOPE_AGENT);
        const unsigned tgt = (unsigned)(t + 1);
        for (;;) {
          unsigned v = __hip_atomic_load(&flags[(lane & 31) * FSTR],
                                         __ATOMIC_RELAXED, __HIP_MEMORY_SCOPE_AGENT);
          if (__all((int)(v >= tgt))) break;
        }
      }
      __builtin_amdgcn_s_barrier();
      asm volatile("" ::: "memory");  // keep next staging loads below the poll
    }
  }
}

extern "C" void kernel_launch(void* const* d_in, const int* in_sizes, int n_in,
                              void* d_out, int out_size, void* d_ws, size_t ws_size,
                              hipStream_t stream) {
  const int* rnn = (const int*)d_in[0];
  const float* sv = (const float*)d_in[1];
  const float* embed = (const float*)d_in[2];
  const float* U_w = (const float*)d_in[3];
  const float* U_b = (const float*)d_in[4];
  const float* S1_w = (const float*)d_in[5];
  const float* S1_b = (const float*)d_in[6];
  const float* V_w = (const float*)d_in[7];
  const float* V_b = (const float*)d_in[8];
  const float* W_w = (const float*)d_in[9];
  const float* W_b = (const float*)d_in[10];
  const float* P_w = (const float*)d_in[11];
  const float* P_b = (const float*)d_in[12];
  float* out = (float*)d_out;

  char* ws = (char*)d_ws;
  size_t off = 0;
  auto alloc = [&](size_t bytes) -> void* {
    void* p = ws + off;
    off += (bytes + 255) & ~(size_t)255;
    return p;
  };
  bf16* Pt = (bf16*)alloc((size_t)NV * NH * 2);           // P_w^T
  float* Gx = (float*)alloc((size_t)MPAD * NG * 4);       // gate preactivations
  bf16* Ub = (bf16*)alloc((size_t)MPAD * NS4 * 2);        // U (bf16)
  bf16* Wt = (bf16*)alloc((size_t)NG * NH * 2);           // W_w^T
  bf16* hb = (bf16*)alloc((size_t)(MPAD + 32) * NH * 2);  // h ring (row0=h0)
  bf16* Vt = (bf16*)alloc((size_t)NG * NS * 2);           // V_w^T
  bf16* Xb = (bf16*)alloc((size_t)MPAD * NE * 2);         // gathered emb
  bf16* Ut = (bf16*)alloc((size_t)NS4 * NE * 2);          // U_w^T
  bf16* S1t = (bf16*)alloc((size_t)NS * NS4 * 2);         // S1_w^T
  bf16* Sb = (bf16*)alloc((size_t)MPAD * NS * 2);         // S (bf16)
  float* vbwb = (float*)alloc((size_t)NG * 4);            // V_b + W_b
  unsigned* flags = (unsigned*)alloc((size_t)RNB * FSTR * 4);  // step flags
  (void)in_sizes; (void)n_in; (void)out_size; (void)ws_size;

  // Phase A0: weight conversion (transpose to [N][K] bf16)
  k_transpose_cvt<<<dim3(NS4 / 32, NE / 32), 256, 0, stream>>>(U_w, Ut, NE, NS4);
  k_transpose_cvt<<<dim3(NS / 32, NS4 / 32), 256, 0, stream>>>(S1_w, S1t, NS4, NS);
  k_transpose_cvt<<<dim3(NG / 32, NS / 32), 256, 0, stream>>>(V_w, Vt, NS, NG);
  k_transpose_cvt<<<dim3(NG / 32, NH / 32), 256, 0, stream>>>(W_w, Wt, NH, NG);
  k_transpose_cvt<<<dim3(NV / 32, NH / 32), 256, 0, stream>>>(P_w, Pt, NH, NV);
  k_bias2<<<NG / 256, 256, 0, stream>>>(V_b, W_b, vbwb);
  k_init<<<(NB * NH + 255) / 256, 256, 0, stream>>>(sv, hb, flags);
  k_gather<<<MPAD, 256, 0, stream>>>(rnn, embed, Xb);

  // Phase A1: batched pre-GEMMs over all (t,b)
  k_gemm<0><<<dim3(NS4 / 128, MPAD / 128), 256, 0, stream>>>(Xb, Ut, U_b, Ub, NE, NS4);
  k_gemm<0><<<dim3(NS / 128, MPAD / 128), 256, 0, stream>>>(Ub, S1t, S1_b, Sb, NS4, NS);
  k_gemm<1><<<dim3(NG / 128, MPAD / 128), 256, 0, stream>>>(Sb, Vt, vbwb, Gx, NS, NG);

  // Phase B: persistent recurrence (single dispatch, fence-free flag barrier)
  k_rnn<<<RNB, 512, 0, stream>>>(Wt, Gx, sv, hb, flags);

  // Phase C: output projection for all (t,b), remapped to out[b][t][v]
  k_gemm<2><<<dim3(NV / 128, MPAD / 128), 256, 0, stream>>>(hb + (size_t)NB * NH, Pt,
                                                            P_b, out, NH, NV);
}